// Round 1
// baseline (1491.696 us; speedup 1.0000x reference)
//
#include <hip/hip_runtime.h>

#define NB 1024
#define NNODE 200
#define NN2 40000
#define HD 128
#define KTOP 8000

// f32 -> bf16 round-to-nearest-even (values are finite, no NaN here)
__device__ __forceinline__ unsigned short f2bf(float f) {
  unsigned u = __float_as_uint(f);
  u = u + 0x7FFFu + ((u >> 16) & 1u);
  return (unsigned short)(u >> 16);
}
__device__ __forceinline__ float bf2f(unsigned short b) {
  return __uint_as_float(((unsigned)b) << 16);
}

// top-k selection predicate: value bits desc, flat index asc (JAX top_k tie-break)
__device__ __forceinline__ float maskv(float v, int idx, unsigned vt, int it) {
  unsigned b = __float_as_uint(v);
  return (b > vt || (b == vt && idx <= it)) ? v : 0.0f;
}

struct alignas(16) SM {
  union {
    struct {
      unsigned hist[1024];
      unsigned cbits[512];  // also reused as coarse-scan sums ts[256]
      int cidx[512];
    } p1;
    struct {
      float xs[8][65];    // P3: x chunk [kk][i_local], padded
      float w1s[8][128];  // P3: W1 chunk
      float ahd[8][65];   // P4: Ah_ij * dinv_i chunk [kk][j_local], padded
    } p34;
  } u;
  unsigned short xw[NNODE * HD];  // XW1 in bf16, [i][h]
  float dinv[NNODE];
  float r[NNODE];
  float gpart[HD];
  int sc[4];
  unsigned vt;
  int it;
  int cnt;
};

__global__ __launch_bounds__(256) void fused_gcn(
    const float* __restrict__ x, const float* __restrict__ W1,
    const float* __restrict__ b1, const float* __restrict__ W2,
    const float* __restrict__ b2, float* __restrict__ out) {
  __shared__ SM sm;
  const int s = blockIdx.x;
  const int tid = threadIdx.x;
  const float* xp = x + (size_t)s * NN2;

  // ================= P1: exact top-8000 threshold (radix select on bits) ====
  // level 1: histogram of bits[31:20]  (values in [0,1) -> bucket <= 1015)
  for (int e = tid; e < 1024; e += 256) sm.u.p1.hist[e] = 0u;
  __syncthreads();
  for (int e = tid; e < NN2; e += 256) {
    unsigned bits = __float_as_uint(xp[e]);
    atomicAdd(&sm.u.p1.hist[bits >> 20], 1u);
  }
  __syncthreads();
  // coarse sums (4 buckets per thread) then scan from top on thread 0
  if (tid < 256) {
    sm.u.p1.cbits[tid] = sm.u.p1.hist[tid * 4] + sm.u.p1.hist[tid * 4 + 1] +
                         sm.u.p1.hist[tid * 4 + 2] + sm.u.p1.hist[tid * 4 + 3];
  }
  __syncthreads();
  if (tid == 0) {
    int cum = 0, b1sel = 0, need = KTOP;
    for (int t = 255; t >= 0; --t) {
      int c = (int)sm.u.p1.cbits[t];
      if (cum + c >= KTOP) {
        int cc = cum;
        for (int b = t * 4 + 3; b >= t * 4; --b) {
          int hb = (int)sm.u.p1.hist[b];
          if (cc + hb >= KTOP) { b1sel = b; need = KTOP - cc; break; }
          cc += hb;
        }
        break;
      }
      cum += c;
    }
    sm.sc[0] = b1sel;
    sm.sc[1] = need;
  }
  __syncthreads();
  const int b1sel = sm.sc[0];
  const int need1 = sm.sc[1];
  // level 2: among bucket b1sel, histogram bits[19:10]
  for (int e = tid; e < 1024; e += 256) sm.u.p1.hist[e] = 0u;
  __syncthreads();
  for (int e = tid; e < NN2; e += 256) {
    unsigned bits = __float_as_uint(xp[e]);
    if ((int)(bits >> 20) == b1sel) atomicAdd(&sm.u.p1.hist[(bits >> 10) & 1023u], 1u);
  }
  __syncthreads();
  if (tid < 256) {
    sm.u.p1.cbits[tid] = sm.u.p1.hist[tid * 4] + sm.u.p1.hist[tid * 4 + 1] +
                         sm.u.p1.hist[tid * 4 + 2] + sm.u.p1.hist[tid * 4 + 3];
  }
  __syncthreads();
  if (tid == 0) {
    int cum = 0, b2sel = 0, need2 = need1;
    for (int t = 255; t >= 0; --t) {
      int c = (int)sm.u.p1.cbits[t];
      if (cum + c >= need1) {
        int cc = cum;
        for (int b = t * 4 + 3; b >= t * 4; --b) {
          int hb = (int)sm.u.p1.hist[b];
          if (cc + hb >= need1) { b2sel = b; need2 = need1 - cc; break; }
          cc += hb;
        }
        break;
      }
      cum += c;
    }
    sm.sc[2] = b2sel;
    sm.sc[3] = need2;
    sm.cnt = 0;
  }
  __syncthreads();
  const unsigned top22 = ((unsigned)b1sel << 10) | (unsigned)sm.sc[2];
  const int need2 = sm.sc[3];
  // level 3: collect candidates sharing top-22 bits, rank by (bits desc, idx asc)
  for (int e = tid; e < NN2; e += 256) {
    unsigned bits = __float_as_uint(xp[e]);
    if ((bits >> 10) == top22) {
      int p = atomicAdd(&sm.cnt, 1);
      if (p < 512) { sm.u.p1.cbits[p] = bits; sm.u.p1.cidx[p] = e; }
    }
  }
  __syncthreads();
  {
    int c = sm.cnt; if (c > 512) c = 512;
    for (int t = tid; t < c; t += 256) {
      unsigned vb = sm.u.p1.cbits[t];
      int vi = sm.u.p1.cidx[t];
      int rank = 0;
      for (int uu = 0; uu < c; ++uu) {
        unsigned ub = sm.u.p1.cbits[uu];
        if (ub > vb || (ub == vb && sm.u.p1.cidx[uu] < vi)) ++rank;
      }
      if (rank == need2 - 1) { sm.vt = vb; sm.it = vi; }
    }
  }
  __syncthreads();
  const unsigned vt = sm.vt;
  const int itx = sm.it;

  // ================= P2: dinv_j = 1/sqrt(1 + colsum_j(A)), r_i = rowsum_i(An)
  if (tid < NNODE) {
    float deg = 1.0f;  // self-loop
    for (int i = 0; i < NNODE; ++i) {
      float v = xp[i * NNODE + tid];
      deg += maskv(v, i * NNODE + tid, vt, itx);
    }
    sm.dinv[tid] = 1.0f / sqrtf(deg);
  }
  __syncthreads();
  if (tid < NNODE) {
    float sum = 0.0f;
    const int base = tid * NNODE;
    for (int j = 0; j < NNODE; ++j) {
      float v = xp[base + j];
      sum += maskv(v, base + j, vt, itx) * sm.dinv[j];
    }
    float di = sm.dinv[tid];
    sm.r[tid] = di * (sum + di);  // + dinv_i for the self-loop term
  }
  if (tid < HD) sm.gpart[tid] = 0.0f;
  __syncthreads();

  // ================= P3: XW = x @ W1  -> LDS bf16 [200][128] ================
  const int th = tid & 31;   // h-group: h = th*4 .. th*4+3
  const int tw = tid >> 5;   // 0..7: 8 rows each within 64-row tile
  for (int i0 = 0; i0 < NNODE; i0 += 64) {
    float acc[8][4];
#pragma unroll
    for (int a = 0; a < 8; ++a)
#pragma unroll
      for (int b = 0; b < 4; ++b) acc[a][b] = 0.0f;
    for (int k0 = 0; k0 < NNODE; k0 += 8) {
      {
        int kk = tid & 7;
        int il = tid >> 3;  // 0..31
#pragma unroll
        for (int rep = 0; rep < 2; ++rep) {
          int ilr = il + rep * 32;
          int gi = i0 + ilr;
          sm.u.p34.xs[kk][ilr] = (gi < NNODE) ? xp[gi * NNODE + k0 + kk] : 0.0f;
        }
      }
      for (int e = tid; e < 1024; e += 256) {
        int kk = e >> 7, h = e & 127;
        sm.u.p34.w1s[kk][h] = W1[(k0 + kk) * HD + h];
      }
      __syncthreads();
#pragma unroll
      for (int kk = 0; kk < 8; ++kk) {
        float4 w4 = *(const float4*)&sm.u.p34.w1s[kk][th * 4];
#pragma unroll
        for (int ii = 0; ii < 8; ++ii) {
          float a = sm.u.p34.xs[kk][tw * 8 + ii];
          acc[ii][0] += a * w4.x;
          acc[ii][1] += a * w4.y;
          acc[ii][2] += a * w4.z;
          acc[ii][3] += a * w4.w;
        }
      }
      __syncthreads();
    }
#pragma unroll
    for (int ii = 0; ii < 8; ++ii) {
      int gi = i0 + tw * 8 + ii;
      if (gi < NNODE) {
        int o = gi * HD + th * 4;
        sm.xw[o + 0] = f2bf(acc[ii][0]);
        sm.xw[o + 1] = f2bf(acc[ii][1]);
        sm.xw[o + 2] = f2bf(acc[ii][2]);
        sm.xw[o + 3] = f2bf(acc[ii][3]);
      }
    }
  }
  __syncthreads();

  // ====== P4: out1_j = dinv_j * sum_i (Ah_ij*dinv_i) XW_i ; h=relu(+b1);
  // ======     g[h] += r_j * h_j[h]   (layer-2 collapsed via node-mean) ======
  for (int j0 = 0; j0 < NNODE; j0 += 64) {
    float acc[8][4];
#pragma unroll
    for (int a = 0; a < 8; ++a)
#pragma unroll
      for (int b = 0; b < 4; ++b) acc[a][b] = 0.0f;
    for (int ib = 0; ib < NNODE; ib += 8) {
      {
        int row = tid >> 5;        // 0..7 (i within chunk)
        int col = (tid & 31) * 2;  // j within tile
        int i = ib + row;
        float di = sm.dinv[i];
#pragma unroll
        for (int cc = 0; cc < 2; ++cc) {
          int j = j0 + col + cc;
          float a = 0.0f;
          if (j < NNODE) {
            float v = xp[i * NNODE + j];
            a = maskv(v, i * NNODE + j, vt, itx);
            if (i == j) a += 1.0f;  // self-loop
            a *= di;
          }
          sm.u.p34.ahd[row][col + cc] = a;
        }
      }
      __syncthreads();
#pragma unroll
      for (int kk = 0; kk < 8; ++kk) {
        ushort4 u4 = *(const ushort4*)&sm.xw[(ib + kk) * HD + th * 4];
        float w0 = bf2f(u4.x), w1v = bf2f(u4.y), w2v = bf2f(u4.z), w3v = bf2f(u4.w);
#pragma unroll
        for (int jj = 0; jj < 8; ++jj) {
          float a = sm.u.p34.ahd[kk][tw * 8 + jj];
          acc[jj][0] += a * w0;
          acc[jj][1] += a * w1v;
          acc[jj][2] += a * w2v;
          acc[jj][3] += a * w3v;
        }
      }
      __syncthreads();
    }
    // epilogue: scale by dinv_j, +b1, relu, weight by r_j, accumulate into g
    float g0 = 0.0f, g1 = 0.0f, g2 = 0.0f, g3 = 0.0f;
    float bb0 = b1[th * 4 + 0], bb1 = b1[th * 4 + 1];
    float bb2 = b1[th * 4 + 2], bb3 = b1[th * 4 + 3];
#pragma unroll
    for (int jj = 0; jj < 8; ++jj) {
      int j = j0 + tw * 8 + jj;
      if (j < NNODE) {
        float dj = sm.dinv[j], rj = sm.r[j];
        float o0 = fmaxf(dj * acc[jj][0] + bb0, 0.0f);
        float o1 = fmaxf(dj * acc[jj][1] + bb1, 0.0f);
        float o2 = fmaxf(dj * acc[jj][2] + bb2, 0.0f);
        float o3 = fmaxf(dj * acc[jj][3] + bb3, 0.0f);
        g0 += rj * o0; g1 += rj * o1; g2 += rj * o2; g3 += rj * o3;
      }
    }
    atomicAdd(&sm.gpart[th * 4 + 0], g0);
    atomicAdd(&sm.gpart[th * 4 + 1], g1);
    atomicAdd(&sm.gpart[th * 4 + 2], g2);
    atomicAdd(&sm.gpart[th * 4 + 3], g3);
  }
  __syncthreads();

  // ================= P5: out = (g @ W2)/N + b2 ==============================
  if (tid < HD) {
    float acc = 0.0f;
    for (int c = 0; c < HD; ++c) acc += sm.gpart[c] * W2[c * HD + tid];
    out[(size_t)s * HD + tid] = acc * (1.0f / (float)NNODE) + b2[tid];
  }
}

extern "C" void kernel_launch(void* const* d_in, const int* in_sizes, int n_in,
                              void* d_out, int out_size, void* d_ws, size_t ws_size,
                              hipStream_t stream) {
  (void)in_sizes; (void)n_in; (void)d_ws; (void)ws_size; (void)out_size;
  const float* x  = (const float*)d_in[0];
  // d_in[1] (adj) is dead: the reference overwrites it with sparse(x, 0.2)
  const float* W1 = (const float*)d_in[2];
  const float* b1 = (const float*)d_in[3];
  const float* W2 = (const float*)d_in[4];
  const float* b2 = (const float*)d_in[5];
  float* out = (float*)d_out;
  fused_gcn<<<dim3(NB), dim3(256), 0, stream>>>(x, W1, b1, W2, b2, out);
}

// Round 2
// 680.936 us; speedup vs baseline: 2.1907x; 2.1907x over previous
//
#include <hip/hip_runtime.h>

#define NB 1024
#define NNODE 200
#define NN2 40000
#define HD 128
#define KTOP 8000
#define KPAD 224   // k padded to 7 chunks of 32
#define NCH 7
#define NJT 13     // j-tiles (208)
#define XBS 232    // xb row stride (elems, 464B: 16B-aligned rows)
#define A2S 40     // a2t row stride (80B aligned)
#define XWS 40     // xwt row stride (80B aligned)

typedef __attribute__((ext_vector_type(8))) short short8;
typedef __attribute__((ext_vector_type(4))) float f32x4;

__device__ __forceinline__ unsigned short f2bf(float f) {
  unsigned u = __float_as_uint(f);
  u = u + 0x7FFFu + ((u >> 16) & 1u);
  return (unsigned short)(u >> 16);
}

// JAX top_k selection predicate: value bits desc, flat index asc
__device__ __forceinline__ float maskv(float v, int idx, unsigned vt, int it) {
  unsigned b = __float_as_uint(v);
  return (b > vt || (b == vt && idx <= it)) ? v : 0.0f;
}

// ===== K0: pack W1 (200x128 f32) into bf16 B-fragment order ================
// frag index t = (ks*8 + ht)*64 + lane; element j: B[k=ks*32+(lane>>4)*8+j][h=ht*16+(lane&15)]
__global__ void k_weights(const float* __restrict__ W1, unsigned short* __restrict__ wf) {
  int t = blockIdx.x * 256 + threadIdx.x;
  if (t >= NCH * 8 * 64) return;
  int lane = t & 63;
  int ht = (t >> 6) & 7;
  int ks = t >> 9;
  int c = lane & 15, q = lane >> 4;
  int h = ht * 16 + c;
  unsigned short v[8];
#pragma unroll
  for (int j = 0; j < 8; ++j) {
    int k = ks * 32 + q * 8 + j;
    v[j] = f2bf((k < NNODE) ? W1[k * HD + h] : 0.0f);
  }
  uint4 u;
  u.x = (unsigned)v[0] | ((unsigned)v[1] << 16);
  u.y = (unsigned)v[2] | ((unsigned)v[3] << 16);
  u.z = (unsigned)v[4] | ((unsigned)v[5] << 16);
  u.w = (unsigned)v[6] | ((unsigned)v[7] << 16);
  ((uint4*)wf)[t] = u;
}

// ===== K1: per-sample select threshold + dinv + r ==========================
__global__ __launch_bounds__(256) void k_prep(const float* __restrict__ x,
                                              unsigned* __restrict__ vtit,
                                              float* __restrict__ dinv_g,
                                              float* __restrict__ r_g) {
  __shared__ unsigned hist[4096];
  __shared__ unsigned csum[256];
  __shared__ unsigned cbits[1024];
  __shared__ int cidx[1024];
  __shared__ float degf[NNODE];
  __shared__ float dinv_sh[NNODE];
  __shared__ int sc2[2];
  __shared__ unsigned svt;
  __shared__ int sit;
  __shared__ int cnt;

  const int s = blockIdx.x;
  const int tid = threadIdx.x;
  const float* xp = x + (size_t)s * NN2;

  // pass 1: histogram of bits[31:18] (x in [0,1) -> bucket <= 4061)
  for (int e = tid; e < 4096; e += 256) hist[e] = 0u;
  if (tid < NNODE) degf[tid] = 0.0f;
  if (tid == 0) cnt = 0;
  __syncthreads();
  for (int e = tid; e < NN2; e += 256) {
    unsigned bits = __float_as_uint(xp[e]);
    atomicAdd(&hist[bits >> 18], 1u);
  }
  __syncthreads();
  if (tid < 256) {
    unsigned ss = 0;
#pragma unroll
    for (int k = 0; k < 16; ++k) ss += hist[tid * 16 + k];
    csum[tid] = ss;
  }
  __syncthreads();
  if (tid == 0) {
    int cum = 0, bsel = 0, need = KTOP;
    for (int t = 255; t >= 0; --t) {
      int c16 = (int)csum[t];
      if (cum + c16 >= KTOP) {
        for (int b = t * 16 + 15; b >= t * 16; --b) {
          int hb = (int)hist[b];
          if (cum + hb >= KTOP) { bsel = b; need = KTOP - cum; break; }
          cum += hb;
        }
        break;
      }
      cum += c16;
    }
    sc2[0] = bsel;
    sc2[1] = need;
  }
  __syncthreads();
  const int bsel = sc2[0];
  const int need = sc2[1];

  // pass 2: collect candidates (bucket==bsel) AND sure colsums (bucket>bsel)
  for (int e = tid; e < NN2; e += 256) {
    float v = xp[e];
    unsigned bits = __float_as_uint(v);
    int bk = (int)(bits >> 18);
    if (bk > bsel) {
      atomicAdd(&degf[e % NNODE], v);
    } else if (bk == bsel) {
      int p = atomicAdd(&cnt, 1);
      if (p < 1024) { cbits[p] = bits; cidx[p] = e; }
    }
  }
  __syncthreads();
  {
    int c = cnt;
    if (c > 1024) c = 1024;
    for (int t = tid; t < c; t += 256) {
      unsigned vb = cbits[t];
      int vi = cidx[t];
      int rank = 0;
      for (int u = 0; u < c; ++u) {
        unsigned ub = cbits[u];
        if (ub > vb || (ub == vb && cidx[u] < vi)) ++rank;
      }
      if (rank == need - 1) { svt = vb; sit = vi; }
    }
  }
  __syncthreads();
  const unsigned vt = svt;
  const int itx = sit;
  // add selected candidates' colsum contributions
  {
    int c = cnt;
    if (c > 1024) c = 1024;
    for (int t = tid; t < c; t += 256) {
      unsigned bits = cbits[t];
      int e = cidx[t];
      if (bits > vt || (bits == vt && e <= itx))
        atomicAdd(&degf[e % NNODE], __uint_as_float(bits));
    }
  }
  __syncthreads();
  if (tid < NNODE) {
    float d = 1.0f / sqrtf(1.0f + degf[tid]);  // +1 self-loop
    dinv_sh[tid] = d;
    dinv_g[s * NNODE + tid] = d;
  }
  if (tid == 0) {
    vtit[s * 2 + 0] = vt;
    vtit[s * 2 + 1] = (unsigned)itx;
  }
  __syncthreads();

  // pass 3: weighted rowsums, wave-per-row (coalesced)
  const int w = tid >> 6;
  const int lane = tid & 63;
  for (int i = w; i < NNODE; i += 4) {
    const int base = i * NNODE;
    float sum = maskv(xp[base + lane], base + lane, vt, itx) * dinv_sh[lane];
    sum += maskv(xp[base + lane + 64], base + lane + 64, vt, itx) * dinv_sh[lane + 64];
    sum += maskv(xp[base + lane + 128], base + lane + 128, vt, itx) * dinv_sh[lane + 128];
    if (lane < NNODE - 192)
      sum += maskv(xp[base + lane + 192], base + lane + 192, vt, itx) * dinv_sh[lane + 192];
#pragma unroll
    for (int m = 1; m < 64; m <<= 1) sum += __shfl_xor(sum, m);
    if (lane == 0) {
      float di = dinv_sh[i];
      r_g[s * NNODE + i] = di * (sum + di);
    }
  }
}

// ===== K2: fused chain GEMM (MFMA) + epilogue ==============================
__global__ __launch_bounds__(512, 4) void k_main(
    const float* __restrict__ x, const unsigned short* __restrict__ wf,
    const float* __restrict__ b1, const float* __restrict__ W2,
    const float* __restrict__ b2, const unsigned* __restrict__ vtit,
    const float* __restrict__ dinv_g, const float* __restrict__ r_g,
    float* __restrict__ out) {
  __shared__ unsigned short xb[32][XBS];     // x chunk, bf16, [i][k]
  __shared__ unsigned short a2t[208][A2S];   // Ah_ij*dinv_i, bf16, [j][i]
  __shared__ unsigned short xwt[HD][XWS];    // XW chunk, bf16, [h][i]
  __shared__ float dinv_l[KPAD];
  __shared__ float r_l[NNODE];
  __shared__ float gs[HD];

  const int s = blockIdx.x;
  const int tid = threadIdx.x;
  const int lane = tid & 63;
  const int w = tid >> 6;       // wave 0..7
  const int c = lane & 15;
  const int q = lane >> 4;
  const float* xp = x + (size_t)s * NN2;

  if (tid < KPAD) dinv_l[tid] = (tid < NNODE) ? dinv_g[s * NNODE + tid] : 0.0f;
  if (tid < NNODE) r_l[tid] = r_g[s * NNODE + tid];
  if (tid < 256) a2t[200 + (tid >> 5)][tid & 31] = 0;  // j-pad rows
  const unsigned vt = vtit[s * 2];
  const int itx = (int)vtit[s * 2 + 1];

  f32x4 acc2[NJT];
#pragma unroll
  for (int jt = 0; jt < NJT; ++jt) acc2[jt] = (f32x4){0.f, 0.f, 0.f, 0.f};

  const int it1 = w & 1;   // GEMM1 i-tile
  const int hb = w >> 1;   // GEMM1 h-tile base (hb, hb+4)
  const short8* bp = (const short8*)wf;

  __syncthreads();

  for (int ic = 0; ic < NCH; ++ic) {
    const int i0 = ic * 32;
    // ---- stage: xb (raw bf16) + a2t (masked, *dinv_i, +I) ----
    {
      const int r = tid >> 4;       // 0..31
      const int c0 = tid & 15;
      const int gi = i0 + r;
      const bool rowok = gi < NNODE;
      const float di = dinv_l[gi];
      const int rb = gi * NNODE;
#pragma unroll
      for (int itc = 0; itc < 13; ++itc) {
        int col = c0 + itc * 16;
        if (col < NNODE) {
          float v = rowok ? xp[rb + col] : 0.0f;
          xb[r][col] = f2bf(v);
          float am = maskv(v, rb + col, vt, itx);
          if (gi == col) am += 1.0f;
          a2t[col][r] = f2bf(am * di);
        }
      }
      xb[r][200 + c0] = 0;  // k-pad
      xb[r][216 + c0] = 0;
    }
    __syncthreads();
    // ---- GEMM1: XWc[i][h] = x[i][:] @ W1 ----
    {
      f32x4 ac0 = {0.f, 0.f, 0.f, 0.f}, ac1 = {0.f, 0.f, 0.f, 0.f};
      const unsigned short* arow = &xb[it1 * 16 + c][q * 8];
#pragma unroll
      for (int ks = 0; ks < NCH; ++ks) {
        short8 af = *(const short8*)(arow + ks * 32);
        short8 b0 = bp[(ks * 8 + hb) * 64 + lane];
        short8 b1f = bp[(ks * 8 + hb + 4) * 64 + lane];
        ac0 = __builtin_amdgcn_mfma_f32_16x16x32_bf16(af, b0, ac0, 0, 0, 0);
        ac1 = __builtin_amdgcn_mfma_f32_16x16x32_bf16(af, b1f, ac1, 0, 0, 0);
      }
      const int ib = it1 * 16 + q * 4;
      uint2 u0, u1;
      u0.x = (unsigned)f2bf(ac0[0]) | ((unsigned)f2bf(ac0[1]) << 16);
      u0.y = (unsigned)f2bf(ac0[2]) | ((unsigned)f2bf(ac0[3]) << 16);
      u1.x = (unsigned)f2bf(ac1[0]) | ((unsigned)f2bf(ac1[1]) << 16);
      u1.y = (unsigned)f2bf(ac1[2]) | ((unsigned)f2bf(ac1[3]) << 16);
      *(uint2*)&xwt[hb * 16 + c][ib] = u0;
      *(uint2*)&xwt[(hb + 4) * 16 + c][ib] = u1;
    }
    __syncthreads();
    // ---- GEMM2: out1[j][h] += a2t[j][i] * xwt[h][i] (wave = h-tile) ----
    {
      short8 bf = *(const short8*)&xwt[w * 16 + c][q * 8];
#pragma unroll
      for (int jt = 0; jt < NJT; ++jt) {
        short8 af = *(const short8*)&a2t[jt * 16 + c][q * 8];
        acc2[jt] = __builtin_amdgcn_mfma_f32_16x16x32_bf16(af, bf, acc2[jt], 0, 0, 0);
      }
    }
    __syncthreads();
  }

  // ---- epilogue: h1 = relu(dinv_j*out1 + b1); g[h] = sum_j r_j*h1 ----
  {
    const float bb = b1[w * 16 + c];
    float gp = 0.0f;
#pragma unroll
    for (int jt = 0; jt < NJT; ++jt) {
#pragma unroll
      for (int rg = 0; rg < 4; ++rg) {
        int j = jt * 16 + q * 4 + rg;
        if (j < NNODE) {
          float o = fmaxf(dinv_l[j] * acc2[jt][rg] + bb, 0.0f);
          gp += r_l[j] * o;
        }
      }
    }
    gp += __shfl_xor(gp, 16);
    gp += __shfl_xor(gp, 32);
    if (q == 0) gs[w * 16 + c] = gp;
  }
  __syncthreads();
  // ---- P5: out = (g @ W2)/N + b2 ----
  if (tid < HD) {
    float a = 0.0f;
    for (int cc = 0; cc < HD; ++cc) a += gs[cc] * W2[cc * HD + tid];
    out[(size_t)s * HD + tid] = a * (1.0f / (float)NNODE) + b2[tid];
  }
}

extern "C" void kernel_launch(void* const* d_in, const int* in_sizes, int n_in,
                              void* d_out, int out_size, void* d_ws, size_t ws_size,
                              hipStream_t stream) {
  (void)in_sizes; (void)n_in; (void)out_size; (void)ws_size;
  const float* x = (const float*)d_in[0];
  // d_in[1] (adj) is dead: reference overwrites it with sparse(x, 0.2)
  const float* W1 = (const float*)d_in[2];
  const float* b1 = (const float*)d_in[3];
  const float* W2 = (const float*)d_in[4];
  const float* b2 = (const float*)d_in[5];
  float* out = (float*)d_out;

  unsigned short* wf = (unsigned short*)d_ws;                  // 57344 B
  unsigned* vtit = (unsigned*)((char*)d_ws + 57344);           // 8192 B
  float* dinv_g = (float*)((char*)d_ws + 65536);               // 819200 B
  float* r_g = (float*)((char*)d_ws + 884736);                 // 819200 B

  k_weights<<<dim3(14), dim3(256), 0, stream>>>(W1, wf);
  k_prep<<<dim3(NB), dim3(256), 0, stream>>>(x, vtit, dinv_g, r_g);
  k_main<<<dim3(NB), dim3(512), 0, stream>>>(x, wf, b1, W2, b2, vtit, dinv_g, r_g, out);
}

// Round 3
// 477.756 us; speedup vs baseline: 3.1223x; 1.4253x over previous
//
#include <hip/hip_runtime.h>

#define NB 1024
#define NNODE 200
#define NN2 40000
#define HD 128
#define KTOP 8000
#define NCH 7     // i-chunks of 32 (224 padded)
#define NJT 13    // j-tiles of 16 (208 padded)
#define XBS 232   // xb row stride (elems; 464 B = 29*16, 16B-aligned rows)
#define A2S 40    // a2t row stride (80 B)

typedef __attribute__((ext_vector_type(8))) short short8;
typedef __attribute__((ext_vector_type(4))) float f32x4;

__device__ __forceinline__ unsigned short f2bf(float f) {
  unsigned u = __float_as_uint(f);
  u = u + 0x7FFFu + ((u >> 16) & 1u);
  return (unsigned short)(u >> 16);
}

// JAX top_k selection predicate: value bits desc, flat index asc
__device__ __forceinline__ float maskv(float v, int idx, unsigned vt, int it) {
  unsigned b = __float_as_uint(v);
  return (b > vt || (b == vt && idx <= it)) ? v : 0.0f;
}

// ===== K0: pack W1 (200x128 f32) into bf16 B-fragment order ================
// frag t = (ks*8 + ht)*64 + lane; elem j: B[k=ks*32+(lane>>4)*8+j][h=ht*16+(lane&15)]
__global__ void k_weights(const float* __restrict__ W1, unsigned short* __restrict__ wf) {
  int t = blockIdx.x * 256 + threadIdx.x;
  if (t >= NCH * 8 * 64) return;
  int lane = t & 63;
  int ht = (t >> 6) & 7;
  int ks = t >> 9;
  int c = lane & 15, q = lane >> 4;
  int h = ht * 16 + c;
  unsigned short v[8];
#pragma unroll
  for (int j = 0; j < 8; ++j) {
    int k = ks * 32 + q * 8 + j;
    v[j] = f2bf((k < NNODE) ? W1[k * HD + h] : 0.0f);
  }
  uint4 u;
  u.x = (unsigned)v[0] | ((unsigned)v[1] << 16);
  u.y = (unsigned)v[2] | ((unsigned)v[3] << 16);
  u.z = (unsigned)v[4] | ((unsigned)v[5] << 16);
  u.w = (unsigned)v[6] | ((unsigned)v[7] << 16);
  ((uint4*)wf)[t] = u;
}

// ===== K1: per-sample exact top-8000 threshold + dinv ======================
__global__ __launch_bounds__(512) void k_prep(const float* __restrict__ x,
                                              unsigned* __restrict__ vtit,
                                              float* __restrict__ dinv_g) {
  __shared__ unsigned hist[4096];
  __shared__ unsigned csA[512];
  __shared__ unsigned cbits[1024];
  __shared__ int cidx[1024];
  __shared__ float degf[NNODE];
  __shared__ unsigned sub[1024];
  __shared__ unsigned c2b[32];
  __shared__ int c2i[32];
  __shared__ int sc[4];
  __shared__ unsigned svt;
  __shared__ int sit;
  __shared__ int cnt, cnt2;

  const int s = blockIdx.x, tid = threadIdx.x;
  const float* xp = x + (size_t)s * NN2;
  const float4* xp4 = (const float4*)xp;

  for (int e = tid; e < 4096; e += 512) hist[e] = 0u;
  if (tid < NNODE) degf[tid] = 0.0f;
  if (tid == 0) { cnt = 0; cnt2 = 0; }
  __syncthreads();
  // pass 1: histogram of bits[31:18]
  for (int e = tid; e < NN2 / 4; e += 512) {
    float4 f = xp4[e];
    atomicAdd(&hist[__float_as_uint(f.x) >> 18], 1u);
    atomicAdd(&hist[__float_as_uint(f.y) >> 18], 1u);
    atomicAdd(&hist[__float_as_uint(f.z) >> 18], 1u);
    atomicAdd(&hist[__float_as_uint(f.w) >> 18], 1u);
  }
  __syncthreads();
  {
    unsigned ss = 0;
#pragma unroll
    for (int k = 0; k < 8; ++k) ss += hist[tid * 8 + k];
    csA[tid] = ss;
  }
  __syncthreads();
  if (tid == 0) {
    int cum = 0, bsel = 0, need = KTOP;
    for (int t = 511; t >= 0; --t) {
      int cs = (int)csA[t];
      if (cum + cs >= KTOP) {
        for (int b = t * 8 + 7; b >= t * 8; --b) {
          int hb = (int)hist[b];
          if (cum + hb >= KTOP) { bsel = b; need = KTOP - cum; break; }
          cum += hb;
        }
        break;
      }
      cum += cs;
    }
    sc[0] = bsel;
    sc[1] = need;
  }
  __syncthreads();
  const int bsel = sc[0], need = sc[1];
  // pass 2: candidates (bucket==bsel) + sure colsums (bucket>bsel)
  for (int e = tid; e < NN2 / 4; e += 512) {
    float4 f = xp4[e];
    int base = e * 4;
    float vv[4] = {f.x, f.y, f.z, f.w};
#pragma unroll
    for (int k = 0; k < 4; ++k) {
      unsigned bits = __float_as_uint(vv[k]);
      int bk = (int)(bits >> 18);
      if (bk > bsel) {
        atomicAdd(&degf[(base + k) % NNODE], vv[k]);
      } else if (bk == bsel) {
        int p = atomicAdd(&cnt, 1);
        if (p < 1024) { cbits[p] = bits; cidx[p] = base + k; }
      }
    }
  }
  for (int e = tid; e < 1024; e += 512) sub[e] = 0u;
  __syncthreads();
  const int c = cnt < 1024 ? cnt : 1024;
  // sub-histogram refinement on candidates: bits[17:8]
  for (int t = tid; t < c; t += 512) atomicAdd(&sub[(cbits[t] >> 8) & 1023u], 1u);
  __syncthreads();
  if (tid < 128) {
    unsigned ss = 0;
#pragma unroll
    for (int k = 0; k < 8; ++k) ss += sub[tid * 8 + k];
    csA[tid] = ss;
  }
  __syncthreads();
  if (tid == 0) {
    int cum = 0, b2 = 0, need2 = need;
    for (int t = 127; t >= 0; --t) {
      int cs = (int)csA[t];
      if (cum + cs >= need) {
        for (int b = t * 8 + 7; b >= t * 8; --b) {
          int hb = (int)sub[b];
          if (cum + hb >= need) { b2 = b; need2 = need - cum; break; }
          cum += hb;
        }
        break;
      }
      cum += cs;
    }
    sc[2] = b2;
    sc[3] = need2;
  }
  __syncthreads();
  const unsigned key = ((unsigned)bsel << 10) | (unsigned)sc[2];
  const int need2 = sc[3];
  for (int t = tid; t < c; t += 512) {
    if ((cbits[t] >> 8) == key) {
      int p = atomicAdd(&cnt2, 1);
      if (p < 32) { c2b[p] = cbits[t]; c2i[p] = cidx[t]; }
    }
  }
  __syncthreads();
  {
    int c2 = cnt2 < 32 ? cnt2 : 32;
    for (int t = tid; t < c2; t += 512) {
      unsigned vb = c2b[t];
      int vi = c2i[t];
      int rank = 0;
      for (int u = 0; u < c2; ++u) {
        unsigned ub = c2b[u];
        if (ub > vb || (ub == vb && c2i[u] < vi)) ++rank;
      }
      if (rank == need2 - 1) { svt = vb; sit = vi; }
    }
  }
  __syncthreads();
  const unsigned vt = svt;
  const int itx = sit;
  // selected candidates' colsum contributions
  for (int t = tid; t < c; t += 512) {
    unsigned bits = cbits[t];
    int e = cidx[t];
    if (bits > vt || (bits == vt && e <= itx))
      atomicAdd(&degf[e % NNODE], __uint_as_float(bits));
  }
  __syncthreads();
  if (tid < NNODE) dinv_g[s * NNODE + tid] = 1.0f / sqrtf(1.0f + degf[tid]);
  if (tid == 0) {
    vtit[s * 2 + 0] = vt;
    vtit[s * 2 + 1] = (unsigned)itx;
  }
}

// ===== K2: fused chain GEMM, wave-self-contained, shfl transpose ===========
__global__ __launch_bounds__(512, 4) void k_main(
    const float* __restrict__ x, const unsigned short* __restrict__ wf,
    const float* __restrict__ b1, const float* __restrict__ W2,
    const float* __restrict__ b2, const unsigned* __restrict__ vtit,
    const float* __restrict__ dinv_g, float* __restrict__ out) {
  __shared__ unsigned short xb[2][32][XBS];    // x chunk bf16 [i][k]
  __shared__ unsigned short a2t[2][208][A2S];  // Ah_ij*dinv_i bf16 [j][i]
  __shared__ float rowsum[224];
  __shared__ float dinv_l[224];
  __shared__ float gs[HD];
  __shared__ float pt[4][HD];

  const int s = blockIdx.x;
  const int tid = threadIdx.x;
  const int lane = tid & 63;
  const int w = tid >> 6;  // wave 0..7 owns h-tile w
  const int c = lane & 15;
  const int q = lane >> 4;
  const float* xp = x + (size_t)s * NN2;

  if (tid < 224) {
    dinv_l[tid] = (tid < NNODE) ? dinv_g[s * NNODE + tid] : 0.0f;
    rowsum[tid] = 0.0f;
  }
  const unsigned vt = vtit[s * 2];
  const int itx = (int)vtit[s * 2 + 1];

  // chunk-invariant W1 B-fragments (L2-hot, 28 VGPRs)
  const short8* bp = (const short8*)wf;
  short8 bfr[NCH];
#pragma unroll
  for (int ks = 0; ks < NCH; ++ks) bfr[ks] = bp[(ks * 8 + w) * 64 + lane];

  f32x4 acc2[NJT];
#pragma unroll
  for (int jt = 0; jt < NJT; ++jt) acc2[jt] = (f32x4){0.f, 0.f, 0.f, 0.f};

  // staging: thread (r=tid>>4, c0=tid&15) handles 13 cols of row ic*32+r
  auto stage = [&](int ic, int b) {
    const int r = tid >> 4, c0 = tid & 15;
    const int gi = ic * 32 + r;
    const bool rowok = gi < NNODE;
    const float di = dinv_l[gi];
    const int rb = gi * NNODE;
    float rs = 0.0f;
#pragma unroll
    for (int itc = 0; itc < 13; ++itc) {
      int col = c0 + itc * 16;  // <= 207
      unsigned short xbv = 0, a2v = 0;
      if (col < NNODE) {
        float v = rowok ? xp[rb + col] : 0.0f;
        xbv = f2bf(v);
        float am = maskv(v, rb + col, vt, itx);
        rs += am * dinv_l[col];
        if (gi == col) am += 1.0f;
        a2v = f2bf(am * di);
      }
      xb[b][r][col] = xbv;
      a2t[b][col][r] = a2v;
    }
    xb[b][r][208 + c0] = 0;  // k-pad 208..223
    atomicAdd(&rowsum[gi], rs);
  };

  __syncthreads();
  stage(0, 0);
  __syncthreads();

  for (int ic = 0; ic < NCH; ++ic) {
    const int cur = ic & 1;
    if (ic + 1 < NCH) stage(ic + 1, cur ^ 1);
    // GEMM1: D(it)[i16][hc] for i-tiles 0,1 of this chunk, h-tile w
    f32x4 a0 = (f32x4){0.f, 0.f, 0.f, 0.f}, a1 = (f32x4){0.f, 0.f, 0.f, 0.f};
#pragma unroll
    for (int ks = 0; ks < NCH; ++ks) {
      short8 af0 = *(const short8*)&xb[cur][c][ks * 32 + q * 8];
      short8 af1 = *(const short8*)&xb[cur][16 + c][ks * 32 + q * 8];
      a0 = __builtin_amdgcn_mfma_f32_16x16x32_bf16(af0, bfr[ks], a0, 0, 0, 0);
      a1 = __builtin_amdgcn_mfma_f32_16x16x32_bf16(af1, bfr[ks], a1, 0, 0, 0);
    }
    // pack C-layout rows (q*4+rg) to bf16 dword pairs
    unsigned pk0[2], pk1[2];
    pk0[0] = (unsigned)f2bf(a0[0]) | ((unsigned)f2bf(a0[1]) << 16);
    pk0[1] = (unsigned)f2bf(a0[2]) | ((unsigned)f2bf(a0[3]) << 16);
    pk1[0] = (unsigned)f2bf(a1[0]) | ((unsigned)f2bf(a1[1]) << 16);
    pk1[1] = (unsigned)f2bf(a1[2]) | ((unsigned)f2bf(a1[3]) << 16);
    // in-register transpose: C-layout -> GEMM2 B-fragment (k=i-local, n=h)
    // target lane (c,q), dword d: src lane = c + 16*((q&1)*2 + (d>>1)),
    // src dword = d&1, tile it = q>>1
    union {
      unsigned u[4];
      short8 s8;
    } ub;
#pragma unroll
    for (int d = 0; d < 4; ++d) {
      int src = c + (((q & 1) * 2 + (d >> 1)) << 4);
      unsigned lo = (unsigned)__shfl((int)pk0[d & 1], src);
      unsigned hi = (unsigned)__shfl((int)pk1[d & 1], src);
      ub.u[d] = (q >= 2) ? hi : lo;
    }
    short8 bf2 = ub.s8;
    // GEMM2: out1[j][h] += a2t[j][i] * xw[i][h]
#pragma unroll
    for (int jt = 0; jt < NJT; ++jt) {
      short8 af = *(const short8*)&a2t[cur][jt * 16 + c][q * 8];
      acc2[jt] = __builtin_amdgcn_mfma_f32_16x16x32_bf16(af, bf2, acc2[jt], 0, 0, 0);
    }
    __syncthreads();
  }

  // epilogue: h1 = relu(dinv_j*out1 + b1); g[h] = sum_j r_j*h1  (layer 2 collapsed)
  {
    const float bb = b1[w * 16 + c];
    float gp = 0.0f;
#pragma unroll
    for (int jt = 0; jt < NJT; ++jt) {
#pragma unroll
      for (int rg = 0; rg < 4; ++rg) {
        int j = jt * 16 + q * 4 + rg;
        if (j < NNODE) {
          float dj = dinv_l[j];
          float rj = dj * (rowsum[j] + dj);
          float o = fmaxf(dj * acc2[jt][rg] + bb, 0.0f);
          gp += rj * o;
        }
      }
    }
    gp += __shfl_xor(gp, 16);
    gp += __shfl_xor(gp, 32);
    if (q == 0) gs[w * 16 + c] = gp;
  }
  __syncthreads();
  // out = (g @ W2)/N + b2 : 4 partial segments then reduce
  {
    int h = tid & 127, seg = tid >> 7;
    float a = 0.0f;
#pragma unroll 8
    for (int cc = seg * 32; cc < seg * 32 + 32; ++cc) a += gs[cc] * W2[cc * HD + h];
    pt[seg][h] = a;
  }
  __syncthreads();
  if (tid < HD) {
    float a = pt[0][tid] + pt[1][tid] + pt[2][tid] + pt[3][tid];
    out[(size_t)s * HD + tid] = a * (1.0f / (float)NNODE) + b2[tid];
  }
}

extern "C" void kernel_launch(void* const* d_in, const int* in_sizes, int n_in,
                              void* d_out, int out_size, void* d_ws, size_t ws_size,
                              hipStream_t stream) {
  (void)in_sizes; (void)n_in; (void)out_size; (void)ws_size;
  const float* x = (const float*)d_in[0];
  // d_in[1] (adj) is dead: reference overwrites it with sparse(x, 0.2)
  const float* W1 = (const float*)d_in[2];
  const float* b1 = (const float*)d_in[3];
  const float* W2 = (const float*)d_in[4];
  const float* b2 = (const float*)d_in[5];
  float* out = (float*)d_out;

  unsigned short* wf = (unsigned short*)d_ws;         // 57344 B
  unsigned* vtit = (unsigned*)((char*)d_ws + 57344);  // 8192 B
  float* dinv_g = (float*)((char*)d_ws + 65536);      // 819200 B

  k_weights<<<dim3(14), dim3(256), 0, stream>>>(W1, wf);
  k_prep<<<dim3(NB), dim3(512), 0, stream>>>(x, vtit, dinv_g);
  k_main<<<dim3(NB), dim3(512), 0, stream>>>(x, wf, b1, W2, b2, vtit, dinv_g, out);
}

// Round 4
// 439.182 us; speedup vs baseline: 3.3965x; 1.0878x over previous
//
#include <hip/hip_runtime.h>

#define NB 1024
#define NNODE 200
#define NN2 40000
#define HD 128
#define KTOP 8000
#define NCH 7     // i-chunks of 32 (224 padded)
#define NJT 13    // j-tiles of 16 (208 padded)
#define XBS 232   // xb row stride (elems; 464 B; dword stride 116 == 20 mod 32 -> 2-way free)
#define A2S 40    // a2t row stride (80 B; dword stride 20 -> 2-way free)

#define WLO_BITS 0x3F47AE14u  // 0.78f
#define WHI_BITS 0x3F51EB85u  // 0.82f
#define CCAP 3072
#define C2CAP 64

typedef __attribute__((ext_vector_type(8))) short short8;
typedef __attribute__((ext_vector_type(4))) float f32x4;

__device__ __forceinline__ unsigned short f2bf(float f) {
  unsigned u = __float_as_uint(f);
  u = u + 0x7FFFu + ((u >> 16) & 1u);
  return (unsigned short)(u >> 16);
}

// JAX top_k selection predicate: value bits desc, flat index asc
__device__ __forceinline__ float maskv(float v, int idx, unsigned vt, int it) {
  unsigned b = __float_as_uint(v);
  return (b > vt || (b == vt && idx <= it)) ? v : 0.0f;
}

// ===== K0: pack W1 (200x128 f32) into bf16 B-fragment order ================
// frag t = (ks*8 + ht)*64 + lane; elem j: B[k=ks*32+(lane>>4)*8+j][h=ht*16+(lane&15)]
__global__ void k_weights(const float* __restrict__ W1, unsigned short* __restrict__ wf) {
  int t = blockIdx.x * 256 + threadIdx.x;
  if (t >= NCH * 8 * 64) return;
  int lane = t & 63;
  int ht = (t >> 6) & 7;
  int ks = t >> 9;
  int c = lane & 15, q = lane >> 4;
  int h = ht * 16 + c;
  unsigned short v[8];
#pragma unroll
  for (int j = 0; j < 8; ++j) {
    int k = ks * 32 + q * 8 + j;
    v[j] = f2bf((k < NNODE) ? W1[k * HD + h] : 0.0f);
  }
  uint4 u;
  u.x = (unsigned)v[0] | ((unsigned)v[1] << 16);
  u.y = (unsigned)v[2] | ((unsigned)v[3] << 16);
  u.z = (unsigned)v[4] | ((unsigned)v[5] << 16);
  u.w = (unsigned)v[6] | ((unsigned)v[7] << 16);
  ((uint4*)wf)[t] = u;
}

// ===== K1: per-sample exact top-8000 threshold + dinv, single x pass =======
// Window trick: threshold of U[0,1] top-20% is 0.80 +- ~0.003 (5 sigma within
// [0.78,0.82]). Elements > 0.82 are surely selected (colsum direct); elements
// in-window go to an exact candidate list; exact rank by (bits desc, idx asc).
// If the window misses (detectable exactly), block-uniform fallback reruns the
// verified two-pass radix select from L3-hot x. Exactness preserved always.
__global__ __launch_bounds__(512) void k_prep(const float* __restrict__ x,
                                              unsigned* __restrict__ vtit,
                                              float* __restrict__ dinv_g) {
  __shared__ union {
    struct { unsigned cb[CCAP]; int ci[CCAP]; } w;  // 24 KB (window + fallback cands)
    unsigned hist[4096];                            // 16 KB (fallback pass 1)
  } u;
  __shared__ unsigned sub[1024];
  __shared__ unsigned csum[512];
  __shared__ float degf[NNODE];
  __shared__ unsigned c2b[C2CAP];
  __shared__ int c2i[C2CAP];
  __shared__ int sc[4];
  __shared__ int cnt, cnt2, nhi_s, fbflag;
  __shared__ unsigned svt;
  __shared__ int sit;

  const int s = blockIdx.x, tid = threadIdx.x;
  const float* xp = x + (size_t)s * NN2;
  const float4* xp4 = (const float4*)xp;

  if (tid < NNODE) degf[tid] = 0.0f;
  if (tid == 0) { cnt = 0; cnt2 = 0; nhi_s = 0; fbflag = 0; }
  __syncthreads();

  // ---- single streaming pass: sure-colsums + window candidates + n_hi ----
  int nhi = 0;
  for (int e = tid; e < NN2 / 4; e += 512) {
    float4 f = xp4[e];
    int base = e * 4;
    float vv[4] = {f.x, f.y, f.z, f.w};
#pragma unroll
    for (int k = 0; k < 4; ++k) {
      unsigned bits = __float_as_uint(vv[k]);
      if (bits > WHI_BITS) {
        atomicAdd(&degf[(base + k) % NNODE], vv[k]);
        ++nhi;
      } else if (bits >= WLO_BITS) {
        int p = atomicAdd(&cnt, 1);
        if (p < CCAP) { u.w.cb[p] = bits; u.w.ci[p] = base + k; }
      }
    }
  }
#pragma unroll
  for (int m = 1; m < 64; m <<= 1) nhi += __shfl_xor(nhi, m);
  if ((tid & 63) == 0) atomicAdd(&nhi_s, nhi);
  __syncthreads();

  const int need = KTOP - nhi_s;
  const int c = cnt;
  bool window_ok = (need >= 1) && (c <= CCAP) && (need <= c);

  if (window_ok) {
    // ---- exact rank within candidates via sub-histogram on bits[21:12] ----
    // window bits span [0x3F47AE14,0x3F51EB85] -> (bits>>12)&1023 in [122,286],
    // monotone, no wrap.
    for (int e = tid; e < 1024; e += 512) sub[e] = 0u;
    __syncthreads();
    for (int t = tid; t < c; t += 512) atomicAdd(&sub[(u.w.cb[t] >> 12) & 1023u], 1u);
    __syncthreads();
    if (tid < 128) {
      unsigned ss = 0;
#pragma unroll
      for (int k = 0; k < 8; ++k) ss += sub[tid * 8 + k];
      csum[tid] = ss;
    }
    __syncthreads();
    if (tid == 0) {
      int cum = 0, b2 = 0, need2 = need;
      for (int t = 127; t >= 0; --t) {
        int cs = (int)csum[t];
        if (cum + cs >= need) {
          for (int b = t * 8 + 7; b >= t * 8; --b) {
            int hb = (int)sub[b];
            if (cum + hb >= need) { b2 = b; need2 = need - cum; break; }
            cum += hb;
          }
          break;
        }
        cum += cs;
      }
      sc[0] = b2;
      sc[1] = need2;
    }
    __syncthreads();
    const unsigned b2 = (unsigned)sc[0];
    const int need2 = sc[1];
    for (int t = tid; t < c; t += 512) {
      if (((u.w.cb[t] >> 12) & 1023u) == b2) {
        int p = atomicAdd(&cnt2, 1);
        if (p < C2CAP) { c2b[p] = u.w.cb[t]; c2i[p] = u.w.ci[t]; }
      }
    }
    __syncthreads();
    if (cnt2 > C2CAP) {
      if (tid == 0) fbflag = 1;
    } else {
      const int c2 = cnt2;
      for (int t = tid; t < c2; t += 512) {
        unsigned vb = c2b[t];
        int vi = c2i[t];
        int rank = 0;
        for (int uu = 0; uu < c2; ++uu) {
          unsigned ub = c2b[uu];
          if (ub > vb || (ub == vb && c2i[uu] < vi)) ++rank;
        }
        if (rank == need2 - 1) { svt = vb; sit = vi; }
      }
    }
    __syncthreads();
    if (!fbflag) {
      // selected in-window candidates complete the colsums
      const unsigned vt = svt;
      const int itx = sit;
      for (int t = tid; t < c; t += 512) {
        unsigned bits = u.w.cb[t];
        int e = u.w.ci[t];
        if (bits > vt || (bits == vt && e <= itx))
          atomicAdd(&degf[e % NNODE], __uint_as_float(bits));
      }
    }
  } else {
    if (tid == 0) fbflag = 1;
    __syncthreads();  // match barrier count shape (block-uniform anyway)
  }
  __syncthreads();

  if (fbflag) {
    // ================= fallback: verified two-pass radix select ============
    if (tid < NNODE) degf[tid] = 0.0f;
    for (int e = tid; e < 4096; e += 512) u.hist[e] = 0u;
    if (tid == 0) { cnt = 0; cnt2 = 0; }
    __syncthreads();
    for (int e = tid; e < NN2 / 4; e += 512) {
      float4 f = xp4[e];
      atomicAdd(&u.hist[__float_as_uint(f.x) >> 18], 1u);
      atomicAdd(&u.hist[__float_as_uint(f.y) >> 18], 1u);
      atomicAdd(&u.hist[__float_as_uint(f.z) >> 18], 1u);
      atomicAdd(&u.hist[__float_as_uint(f.w) >> 18], 1u);
    }
    __syncthreads();
    {
      unsigned ss = 0;
#pragma unroll
      for (int k = 0; k < 8; ++k) ss += u.hist[tid * 8 + k];
      csum[tid] = ss;
    }
    __syncthreads();
    if (tid == 0) {
      int cum = 0, bsel = 0, nd = KTOP;
      for (int t = 511; t >= 0; --t) {
        int cs = (int)csum[t];
        if (cum + cs >= KTOP) {
          for (int b = t * 8 + 7; b >= t * 8; --b) {
            int hb = (int)u.hist[b];
            if (cum + hb >= KTOP) { bsel = b; nd = KTOP - cum; break; }
            cum += hb;
          }
          break;
        }
        cum += cs;
      }
      sc[0] = bsel;
      sc[1] = nd;
    }
    __syncthreads();
    const int bsel = sc[0], nd = sc[1];
    // pass 2: candidates (bucket==bsel) + sure colsums (bucket>bsel)
    // (overwrites u.hist region via u.w.cb/ci -- hist no longer needed)
    for (int e = tid; e < NN2 / 4; e += 512) {
      float4 f = xp4[e];
      int base = e * 4;
      float vv[4] = {f.x, f.y, f.z, f.w};
#pragma unroll
      for (int k = 0; k < 4; ++k) {
        unsigned bits = __float_as_uint(vv[k]);
        int bk = (int)(bits >> 18);
        if (bk > bsel) {
          atomicAdd(&degf[(base + k) % NNODE], vv[k]);
        } else if (bk == bsel) {
          int p = atomicAdd(&cnt, 1);
          if (p < CCAP) { u.w.cb[p] = bits; u.w.ci[p] = base + k; }
        }
      }
    }
    for (int e = tid; e < 1024; e += 512) sub[e] = 0u;
    __syncthreads();
    const int cc = cnt < CCAP ? cnt : CCAP;
    for (int t = tid; t < cc; t += 512) atomicAdd(&sub[(u.w.cb[t] >> 8) & 1023u], 1u);
    __syncthreads();
    if (tid < 128) {
      unsigned ss = 0;
#pragma unroll
      for (int k = 0; k < 8; ++k) ss += sub[tid * 8 + k];
      csum[tid] = ss;
    }
    __syncthreads();
    if (tid == 0) {
      int cum = 0, b2 = 0, need2 = nd;
      for (int t = 127; t >= 0; --t) {
        int cs = (int)csum[t];
        if (cum + cs >= nd) {
          for (int b = t * 8 + 7; b >= t * 8; --b) {
            int hb = (int)sub[b];
            if (cum + hb >= nd) { b2 = b; need2 = nd - cum; break; }
            cum += hb;
          }
          break;
        }
        cum += cs;
      }
      sc[2] = b2;
      sc[3] = need2;
    }
    __syncthreads();
    const unsigned key = ((unsigned)bsel << 10) | (unsigned)sc[2];
    const int need2 = sc[3];
    for (int t = tid; t < cc; t += 512) {
      if ((u.w.cb[t] >> 8) == key) {
        int p = atomicAdd(&cnt2, 1);
        if (p < C2CAP) { c2b[p] = u.w.cb[t]; c2i[p] = u.w.ci[t]; }
      }
    }
    __syncthreads();
    {
      int c2 = cnt2 < C2CAP ? cnt2 : C2CAP;
      for (int t = tid; t < c2; t += 512) {
        unsigned vb = c2b[t];
        int vi = c2i[t];
        int rank = 0;
        for (int uu = 0; uu < c2; ++uu) {
          unsigned ub = c2b[uu];
          if (ub > vb || (ub == vb && c2i[uu] < vi)) ++rank;
        }
        if (rank == need2 - 1) { svt = vb; sit = vi; }
      }
    }
    __syncthreads();
    const unsigned vt = svt;
    const int itx = sit;
    for (int t = tid; t < cc; t += 512) {
      unsigned bits = u.w.cb[t];
      int e = u.w.ci[t];
      if (bits > vt || (bits == vt && e <= itx))
        atomicAdd(&degf[e % NNODE], __uint_as_float(bits));
    }
    __syncthreads();
  }

  if (tid < NNODE) dinv_g[s * NNODE + tid] = 1.0f / sqrtf(1.0f + degf[tid]);
  if (tid == 0) {
    vtit[s * 2 + 0] = svt;
    vtit[s * 2 + 1] = (unsigned)sit;
  }
}

// ===== K2: fused chain GEMM, wave-self-contained, shfl transpose ===========
__global__ __launch_bounds__(512, 4) void k_main(
    const float* __restrict__ x, const unsigned short* __restrict__ wf,
    const float* __restrict__ b1, const float* __restrict__ W2,
    const float* __restrict__ b2, const unsigned* __restrict__ vtit,
    const float* __restrict__ dinv_g, float* __restrict__ out) {
  __shared__ unsigned short xb[2][32][XBS];    // x chunk bf16 [i][k]
  __shared__ unsigned short a2t[2][208][A2S];  // Ah_ij*dinv_i bf16 [j][i]
  __shared__ float rowsum[224];
  __shared__ float dinv_l[224];
  __shared__ float gs[HD];
  __shared__ float pt[4][HD];

  const int s = blockIdx.x;
  const int tid = threadIdx.x;
  const int lane = tid & 63;
  const int w = tid >> 6;  // wave 0..7 owns h-tile w
  const int c = lane & 15;
  const int q = lane >> 4;
  const float* xp = x + (size_t)s * NN2;

  if (tid < 224) {
    dinv_l[tid] = (tid < NNODE) ? dinv_g[s * NNODE + tid] : 0.0f;
    rowsum[tid] = 0.0f;
  }
  const unsigned vt = vtit[s * 2];
  const int itx = (int)vtit[s * 2 + 1];

  // chunk-invariant W1 B-fragments (L2-hot, 28 VGPRs)
  const short8* bp = (const short8*)wf;
  short8 bfr[NCH];
#pragma unroll
  for (int ks = 0; ks < NCH; ++ks) bfr[ks] = bp[(ks * 8 + w) * 64 + lane];

  f32x4 acc2[NJT];
#pragma unroll
  for (int jt = 0; jt < NJT; ++jt) acc2[jt] = (f32x4){0.f, 0.f, 0.f, 0.f};

  // staging: thread (r=tid>>4, c0=tid&15) handles 13 cols of row ic*32+r
  auto stage = [&](int ic, int b) {
    const int r = tid >> 4, c0 = tid & 15;
    const int gi = ic * 32 + r;
    const bool rowok = gi < NNODE;
    const float di = dinv_l[gi];
    const int rb = gi * NNODE;
    float rs = 0.0f;
#pragma unroll
    for (int itc = 0; itc < 13; ++itc) {
      int col = c0 + itc * 16;  // <= 207
      unsigned short xbv = 0, a2v = 0;
      if (col < NNODE) {
        float v = rowok ? xp[rb + col] : 0.0f;
        xbv = f2bf(v);
        float am = maskv(v, rb + col, vt, itx);
        rs += am * dinv_l[col];
        if (gi == col) am += 1.0f;
        a2v = f2bf(am * di);
      }
      xb[b][r][col] = xbv;
      a2t[b][col][r] = a2v;
    }
    xb[b][r][208 + c0] = 0;  // k-pad 208..223
    atomicAdd(&rowsum[gi], rs);
  };

  __syncthreads();
  stage(0, 0);
  __syncthreads();

  for (int ic = 0; ic < NCH; ++ic) {
    const int cur = ic & 1;
    if (ic + 1 < NCH) stage(ic + 1, cur ^ 1);
    // GEMM1: D(it)[i16][hc] for i-tiles 0,1 of this chunk, h-tile w
    f32x4 a0 = (f32x4){0.f, 0.f, 0.f, 0.f}, a1 = (f32x4){0.f, 0.f, 0.f, 0.f};
#pragma unroll
    for (int ks = 0; ks < NCH; ++ks) {
      short8 af0 = *(const short8*)&xb[cur][c][ks * 32 + q * 8];
      short8 af1 = *(const short8*)&xb[cur][16 + c][ks * 32 + q * 8];
      a0 = __builtin_amdgcn_mfma_f32_16x16x32_bf16(af0, bfr[ks], a0, 0, 0, 0);
      a1 = __builtin_amdgcn_mfma_f32_16x16x32_bf16(af1, bfr[ks], a1, 0, 0, 0);
    }
    // pack C-layout rows (q*4+rg) to bf16 dword pairs
    unsigned pk0[2], pk1[2];
    pk0[0] = (unsigned)f2bf(a0[0]) | ((unsigned)f2bf(a0[1]) << 16);
    pk0[1] = (unsigned)f2bf(a0[2]) | ((unsigned)f2bf(a0[3]) << 16);
    pk1[0] = (unsigned)f2bf(a1[0]) | ((unsigned)f2bf(a1[1]) << 16);
    pk1[1] = (unsigned)f2bf(a1[2]) | ((unsigned)f2bf(a1[3]) << 16);
    // in-register transpose: C-layout -> GEMM2 B-fragment (k=i-local, n=h)
    union {
      unsigned u[4];
      short8 s8;
    } ub;
#pragma unroll
    for (int d = 0; d < 4; ++d) {
      int src = c + (((q & 1) * 2 + (d >> 1)) << 4);
      unsigned lo = (unsigned)__shfl((int)pk0[d & 1], src);
      unsigned hi = (unsigned)__shfl((int)pk1[d & 1], src);
      ub.u[d] = (q >= 2) ? hi : lo;
    }
    short8 bf2 = ub.s8;
    // GEMM2: out1[j][h] += a2t[j][i] * xw[i][h]
#pragma unroll
    for (int jt = 0; jt < NJT; ++jt) {
      short8 af = *(const short8*)&a2t[cur][jt * 16 + c][q * 8];
      acc2[jt] = __builtin_amdgcn_mfma_f32_16x16x32_bf16(af, bf2, acc2[jt], 0, 0, 0);
    }
    __syncthreads();
  }

  // epilogue: h1 = relu(dinv_j*out1 + b1); g[h] = sum_j r_j*h1  (layer 2 collapsed)
  {
    const float bb = b1[w * 16 + c];
    float gp = 0.0f;
#pragma unroll
    for (int jt = 0; jt < NJT; ++jt) {
#pragma unroll
      for (int rg = 0; rg < 4; ++rg) {
        int j = jt * 16 + q * 4 + rg;
        if (j < NNODE) {
          float dj = dinv_l[j];
          float rj = dj * (rowsum[j] + dj);
          float o = fmaxf(dj * acc2[jt][rg] + bb, 0.0f);
          gp += rj * o;
        }
      }
    }
    gp += __shfl_xor(gp, 16);
    gp += __shfl_xor(gp, 32);
    if (q == 0) gs[w * 16 + c] = gp;
  }
  __syncthreads();
  // out = (g @ W2)/N + b2 : 4 partial segments then reduce
  {
    int h = tid & 127, seg = tid >> 7;
    float a = 0.0f;
#pragma unroll 8
    for (int cc = seg * 32; cc < seg * 32 + 32; ++cc) a += gs[cc] * W2[cc * HD + h];
    pt[seg][h] = a;
  }
  __syncthreads();
  if (tid < HD) {
    float a = pt[0][tid] + pt[1][tid] + pt[2][tid] + pt[3][tid];
    out[(size_t)s * HD + tid] = a * (1.0f / (float)NNODE) + b2[tid];
  }
}

extern "C" void kernel_launch(void* const* d_in, const int* in_sizes, int n_in,
                              void* d_out, int out_size, void* d_ws, size_t ws_size,
                              hipStream_t stream) {
  (void)in_sizes; (void)n_in; (void)out_size; (void)ws_size;
  const float* x = (const float*)d_in[0];
  // d_in[1] (adj) is dead: reference overwrites it with sparse(x, 0.2)
  const float* W1 = (const float*)d_in[2];
  const float* b1 = (const float*)d_in[3];
  const float* W2 = (const float*)d_in[4];
  const float* b2 = (const float*)d_in[5];
  float* out = (float*)d_out;

  unsigned short* wf = (unsigned short*)d_ws;         // 57344 B
  unsigned* vtit = (unsigned*)((char*)d_ws + 57344);  // 8192 B
  float* dinv_g = (float*)((char*)d_ws + 65536);      // 819200 B

  k_weights<<<dim3(14), dim3(256), 0, stream>>>(W1, wf);
  k_prep<<<dim3(NB), dim3(512), 0, stream>>>(x, vtit, dinv_g);
  k_main<<<dim3(NB), dim3(512), 0, stream>>>(x, wf, b1, W2, b2, vtit, dinv_g, out);
}